// Round 4
// baseline (16753.076 us; speedup 1.0000x reference)
//
#include <hip/hip_runtime.h>
#include <hip/hip_bf16.h>

// LSTM for MI355X (gfx950) — R4.
// Phase 0 (conv_wih): Wih fp32 -> bf16 (2 MB) once.
// Phase 1 (gemm_xproj2): one WG per timestep s; x[s] staged once in LDS
//   (x read exactly once from HBM — fixes R3's 16x re-fetch ~2.4ms);
//   each wave computes one gate type (512 rows) with bf16 weights from L2.
// Phase 2 (lstm_recur): 64 persistent WGs. Serial-chain fixes:
//   - phase-H h-fetch: 16 inline-asm global_load_dwordx4 sc1 from one base
//     (batched, ONE L3 round trip) instead of 32 issue-serialized atomic
//     loads (~4us/step).  s_waitcnt vmcnt(0) + sched_barrier(0) before MFMAs.
//   - Whh fragments hoisted to registers once (1 wave/SIMD -> VGPRs free);
//     zero LDS reads in the K-loop.
//   - per-wave flags (256/step): no __syncthreads on the critical path.

#define SEQ 2048
#define BAT 64
#define DIN 512
#define HID 512
#define NWG 64
#define HS  8
#define NG  32         // gate slots per recurrence WG (4 types x 8 hidden)
#define WSS 520        // LDS weight row stride (bf16)
#define XSS 520        // LDS x row stride (bf16)
#define GLS 34         // gl row stride (floats)
#define CSS 10         // cs row stride (floats)

typedef short v8s __attribute__((ext_vector_type(8)));
typedef float v4f __attribute__((ext_vector_type(4)));
typedef unsigned int u32x4 __attribute__((ext_vector_type(4)));
typedef unsigned long long u64;

__device__ __forceinline__ unsigned short f2bf(float f) {
  unsigned int u = __builtin_bit_cast(unsigned int, f);
  u += 0x7fffu + ((u >> 16) & 1u);
  return (unsigned short)(u >> 16);
}
__device__ __forceinline__ float bf2f(unsigned short u) {
  unsigned int v = ((unsigned int)u) << 16;
  return __builtin_bit_cast(float, v);
}
__device__ __forceinline__ float sigm(float v)  { return 1.0f / (1.0f + __expf(-v)); }
__device__ __forceinline__ float tanha(float v) { return 1.0f - 2.0f / (__expf(2.0f * v) + 1.0f); }

// ---------------- Phase 0: Wih fp32 -> bf16 ----------------
__global__ __launch_bounds__(256) void conv_wih(
    const float* __restrict__ Wih, unsigned short* __restrict__ wbf)
{
  size_t i = ((size_t)blockIdx.x * 256 + threadIdx.x) * 4;   // 1024 WGs cover 4H*DIN
  float4 v = *(const float4*)(Wih + i);
  *(ushort4*)(wbf + i) = make_ushort4(f2bf(v.x), f2bf(v.y), f2bf(v.z), f2bf(v.w));
}

// ---------------- Phase 1: x-projection GEMM, one WG per s ----------------
__global__ __launch_bounds__(256, 1) void gemm_xproj2(
    const float* __restrict__ x, const unsigned short* __restrict__ wbf,
    unsigned short* __restrict__ xp)
{
  __shared__ unsigned short xs[BAT * XSS];    // 66,560 B
  const int tid = threadIdx.x;
  const int s   = blockIdx.x;

  for (int it = tid; it < BAT * DIN / 4; it += 256) {
    int m = it >> 7;
    int k = (it & 127) * 4;
    float4 v = *(const float4*)(x + ((size_t)s * BAT + m) * DIN + k);
    *(ushort4*)(xs + m * XSS + k) = make_ushort4(f2bf(v.x), f2bf(v.y), f2bf(v.z), f2bf(v.w));
  }
  __syncthreads();

  const int wv = tid >> 6, ln = tid & 63, l15 = ln & 15, lg = ln >> 4;
  // wave wv computes gate type wv: global gate rows [wv*512, wv*512+512)
  for (int ch = 0; ch < 16; ++ch) {           // 32 hidden units per chunk
    const unsigned short* w0 = wbf + ((size_t)(wv * 512 + ch * 32 + l15)) * DIN + lg * 8;
    const unsigned short* w1 = w0 + (size_t)16 * DIN;
    v4f acc[4][2] = {};
    #pragma unroll
    for (int kc = 0; kc < DIN; kc += 32) {
      v8s b0 = *(const v8s*)(w0 + kc);
      v8s b1 = *(const v8s*)(w1 + kc);
      #pragma unroll
      for (int bg = 0; bg < 4; ++bg) {
        v8s a = *(const v8s*)(xs + (bg * 16 + l15) * XSS + lg * 8 + kc);
        acc[bg][0] = __builtin_amdgcn_mfma_f32_16x16x32_bf16(a, b0, acc[bg][0], 0, 0, 0);
        acc[bg][1] = __builtin_amdgcn_mfma_f32_16x16x32_bf16(a, b1, acc[bg][1], 0, 0, 0);
      }
    }
    // epilogue: C/D layout col=lane&15, row=(lane>>4)*4+reg.
    // hidden hi0 = ch*32+l15 (acc[*][0]), hi1 = hi0+16 (acc[*][1]).
    // xp[s][j=hi>>3][b][wv*8 + (hi&7)]  (2B stores; partial lines absorbed by L2 WB)
    int hi0 = ch * 32 + l15, hi1 = hi0 + 16;
    #pragma unroll
    for (int bg = 0; bg < 4; ++bg) {
      #pragma unroll
      for (int r = 0; r < 4; ++r) {
        int m = bg * 16 + lg * 4 + r;
        xp[(((size_t)s * NWG + (hi0 >> 3)) * BAT + m) * NG + wv * 8 + (hi0 & 7)] = f2bf(acc[bg][0][r]);
        xp[(((size_t)s * NWG + (hi1 >> 3)) * BAT + m) * NG + wv * 8 + (hi1 & 7)] = f2bf(acc[bg][1][r]);
      }
    }
  }
}

// ---------------- Phase 2: persistent recurrence ----------------
#define HL(i, OFF) asm volatile("global_load_dwordx4 %0, %1, off offset:" #OFF " sc1" \
                                : "=v"(hq[i]) : "v"(hra) : "memory")

__global__ __launch_bounds__(256, 1) void lstm_recur(
    const float* __restrict__ Whh, const float* __restrict__ bih,
    const float* __restrict__ bhh, const unsigned short* __restrict__ xp,
    float* __restrict__ out, unsigned int* __restrict__ flags,
    unsigned short* __restrict__ hbuf)
{
  __shared__ unsigned short Wh[NG * WSS];     // 33,280 B (init staging only)
  __shared__ float gl[BAT * GLS];
  __shared__ float cs[BAT * CSS];
  __shared__ float bias[NG];

  const int tid = threadIdx.x;
  const int j   = blockIdx.x;
  const int hb  = j * HS;

  for (int idx = tid; idx < NG * 128; idx += 256) {
    int r = idx >> 7;
    int k = (idx & 127) * 4;
    int grow = (r >> 3) * HID + hb + (r & 7);
    float4 b = *(const float4*)(Whh + (size_t)grow * HID + k);
    *(ushort4*)(Wh + r * WSS + k) = make_ushort4(f2bf(b.x), f2bf(b.y), f2bf(b.z), f2bf(b.w));
  }
  if (tid < NG) {
    int grow = (tid >> 3) * HID + hb + (tid & 7);
    bias[tid] = bih[grow] + bhh[grow];
  }
  for (int i = tid; i < BAT * CSS; i += 256) cs[i] = 0.0f;
  __syncthreads();

  const int wv = tid >> 6, ln = tid & 63, l15 = ln & 15, lg = ln >> 4;
  const int m0 = wv * 16;
  const int cm = m0 + (ln >> 2);
  const int ch = (ln & 3) * 2;

  // ---- hoist Whh fragments into registers for the whole kernel (128 VGPR;
  //      1 wave/SIMD so the 512-VGPR budget easily covers it) ----
  v8s wf0[16], wf1[16];
  {
    const unsigned short* Whp0 = Wh + l15 * WSS + lg * 8;
    const unsigned short* Whp1 = Wh + (16 + l15) * WSS + lg * 8;
    #pragma unroll
    for (int i = 0; i < 16; ++i) {
      wf0[i] = *(const v8s*)(Whp0 + i * 32);
      wf1[i] = *(const v8s*)(Whp1 + i * 32);
    }
  }

  for (int t = 0; t < SEQ; ++t) {
    // ---- xp loads: plain (written by previous dispatch), issued before poll ----
    const unsigned short* xpb = xp + (((size_t)t * NWG + j) * BAT + cm) * NG + ch;
    unsigned int xgi = *(const unsigned int*)(xpb);
    unsigned int xgf = *(const unsigned int*)(xpb + 8);
    unsigned int xgg = *(const unsigned int*)(xpb + 16);
    unsigned int xgo = *(const unsigned int*)(xpb + 24);

    v4f a0e = {0,0,0,0}, a0o = {0,0,0,0}, a1e = {0,0,0,0}, a1o = {0,0,0,0};
    if (t > 0) {
      // ---- poll 256 per-wave flags: 2 u64 loads/lane + ballot ----
      const u64* fb = (const u64*)(flags + (size_t)(t - 1) * 256);
      u64 tgt = ((u64)(unsigned)t << 32) | (unsigned)t;
      for (;;) {
        u64 f0 = __hip_atomic_load(fb + 2 * ln,     __ATOMIC_RELAXED, __HIP_MEMORY_SCOPE_AGENT);
        u64 f1 = __hip_atomic_load(fb + 2 * ln + 1, __ATOMIC_RELAXED, __HIP_MEMORY_SCOPE_AGENT);
        if (__ballot((f0 == tgt) && (f1 == tgt)) == ~0ull) break;
        __builtin_amdgcn_s_sleep(1);
      }
      asm volatile("" ::: "memory");   // pin h-loads after the poll

      // ---- phase H: batched sc1 h-fetch — 16 dwordx4 from one base, ONE
      //      round trip; then reg-only MFMAs ----
      u32x4 hq[16];
      const unsigned short* hr = hbuf + ((size_t)((t - 1) & 1)) * (BAT * HID)
                               + (size_t)(m0 + l15) * HID + lg * 8;
      u64 hra = (u64)hr;
      HL(0, 0);    HL(1, 64);   HL(2, 128);  HL(3, 192);
      HL(4, 256);  HL(5, 320);  HL(6, 384);  HL(7, 448);
      HL(8, 512);  HL(9, 576);  HL(10, 640); HL(11, 704);
      HL(12, 768); HL(13, 832); HL(14, 896); HL(15, 960);
      asm volatile("s_waitcnt vmcnt(0)" ::: "memory");
      __builtin_amdgcn_sched_barrier(0);   // rule #18: keep MFMAs below the wait
      #pragma unroll
      for (int i = 0; i < 16; i += 2) {
        v8s ae = __builtin_bit_cast(v8s, hq[i]);
        v8s ao = __builtin_bit_cast(v8s, hq[i + 1]);
        a0e = __builtin_amdgcn_mfma_f32_16x16x32_bf16(ae, wf0[i],     a0e, 0, 0, 0);
        a1e = __builtin_amdgcn_mfma_f32_16x16x32_bf16(ae, wf1[i],     a1e, 0, 0, 0);
        a0o = __builtin_amdgcn_mfma_f32_16x16x32_bf16(ao, wf0[i + 1], a0o, 0, 0, 0);
        a1o = __builtin_amdgcn_mfma_f32_16x16x32_bf16(ao, wf1[i + 1], a1o, 0, 0, 0);
      }
    }
    v4f acc0 = a0e + a0o, acc1 = a1e + a1o;

    // ---- epilogue: C-frags -> gl (wave-private rows) ----
    {
      int mrow = m0 + lg * 4;
      #pragma unroll
      for (int r = 0; r < 4; ++r) {
        gl[(mrow + r) * GLS + l15]      = acc0[r];
        gl[(mrow + r) * GLS + 16 + l15] = acc1[r];
      }
    }

    // ---- cell update: 2 cells per lane (static indexing) ----
    float2 hv, cv;
    {
      const float* gr = gl + cm * GLS;
      float* csp = cs + cm * CSS + ch;
      float xi0 = bf2f((unsigned short)(xgi & 0xffffu)), xi1 = bf2f((unsigned short)(xgi >> 16));
      float xf0 = bf2f((unsigned short)(xgf & 0xffffu)), xf1 = bf2f((unsigned short)(xgf >> 16));
      float xg0 = bf2f((unsigned short)(xgg & 0xffffu)), xg1 = bf2f((unsigned short)(xgg >> 16));
      float xo0 = bf2f((unsigned short)(xgo & 0xffffu)), xo1 = bf2f((unsigned short)(xgo >> 16));
      {
        float gi = gr[ch]      + bias[ch]      + xi0;
        float gf = gr[8 + ch]  + bias[8 + ch]  + xf0;
        float gg = gr[16 + ch] + bias[16 + ch] + xg0;
        float go = gr[24 + ch] + bias[24 + ch] + xo0;
        float c  = sigm(gf) * csp[0] + sigm(gi) * tanha(gg);
        csp[0] = c; cv.x = c; hv.x = sigm(go) * tanha(c);
      }
      {
        int hh = ch + 1;
        float gi = gr[hh]      + bias[hh]      + xi1;
        float gf = gr[8 + hh]  + bias[8 + hh]  + xf1;
        float gg = gr[16 + hh] + bias[16 + hh] + xg1;
        float go = gr[24 + hh] + bias[24 + hh] + xo1;
        float c  = sigm(gf) * csp[1] + sigm(gi) * tanha(gg);
        csp[1] = c; cv.y = c; hv.y = sigm(go) * tanha(c);
      }
    }

    // ---- publish h pair (sc1), per-WAVE drain + flag (no __syncthreads) ----
    {
      unsigned int hp = (unsigned int)f2bf(hv.x) | ((unsigned int)f2bf(hv.y) << 16);
      unsigned short* hd = hbuf + ((size_t)(t & 1)) * (BAT * HID)
                         + (size_t)cm * HID + hb + ch;
      __hip_atomic_store((unsigned int*)hd, hp, __ATOMIC_RELAXED,
                         __HIP_MEMORY_SCOPE_AGENT);
    }
    asm volatile("s_waitcnt vmcnt(0)" ::: "memory");  // h stores (and my phase-H reads) retired
    if (ln == 0) {
      __hip_atomic_store(flags + (size_t)t * 256 + j * 4 + wv, (unsigned int)(t + 1),
                         __ATOMIC_RELAXED, __HIP_MEMORY_SCOPE_AGENT);
    }

    // ---- out stores after publish (off the critical path) ----
    {
      size_t o = ((size_t)t * BAT + cm) * HID + hb + ch;
      *(float2*)(out + o) = hv;
      *(float2*)(out + (size_t)SEQ * BAT * HID + o) = cv;
    }
  }
}

extern "C" void kernel_launch(void* const* d_in, const int* in_sizes, int n_in,
                              void* d_out, int out_size, void* d_ws, size_t ws_size,
                              hipStream_t stream) {
  const float* x   = (const float*)d_in[0];
  const float* Wih = (const float*)d_in[1];
  const float* Whh = (const float*)d_in[2];
  const float* bih = (const float*)d_in[3];
  const float* bhh = (const float*)d_in[4];
  float* out = (float*)d_out;

  const size_t flags_b = (size_t)SEQ * 256 * sizeof(unsigned int);          // 2 MB
  const size_t hbuf_b  = (size_t)2 * BAT * HID * sizeof(unsigned short);    // 128 KB
  const size_t hbuf_pad = 256 * 1024;                                       // pad region
  const size_t wbf_b   = (size_t)4 * HID * DIN * sizeof(unsigned short);    // 2 MB

  unsigned int*   flags = (unsigned int*)d_ws;
  unsigned short* hbuf  = (unsigned short*)((char*)d_ws + flags_b);
  unsigned short* wbf   = (unsigned short*)((char*)d_ws + flags_b + hbuf_pad);
  unsigned short* xp    = (unsigned short*)((char*)d_ws + flags_b + hbuf_pad + wbf_b);
  // total: 2MB + 256KB + 2MB + 512MB ≈ 516.3 MB  (< 537.5 MB proven in R3)
  (void)hbuf_b;

  hipMemsetAsync(d_ws, 0, flags_b, stream);
  hipLaunchKernelGGL(conv_wih,    dim3(1024),  dim3(256), 0, stream, Wih, wbf);
  hipLaunchKernelGGL(gemm_xproj2, dim3(SEQ),   dim3(256), 0, stream, x, wbf, xp);
  hipLaunchKernelGGL(lstm_recur,  dim3(NWG),   dim3(256), 0, stream,
                     Whh, bih, bhh, xp, out, flags, hbuf);
}